// Round 3
// baseline (462.160 us; speedup 1.0000x reference)
//
#include <hip/hip_runtime.h>

// out = clip(x + laplace_noise * mask, 0, 1), element-wise over
// N = 256*3*224*224 = 38,535,168 fp32 elements (n4 = 9,633,792 float4).
// Memory-bound. Round-3: same as round-2 (grid-stride 4x unroll for MLP +
// nontemporal stores) but using clang ext_vector_type instead of HIP's
// float4 class — __builtin_nontemporal_store requires a native vector type.

typedef float fvec4 __attribute__((ext_vector_type(4)));

__device__ __forceinline__ fvec4 clip_fma(fvec4 l, fvec4 m, fvec4 xv) {
    fvec4 o;
    o.x = fminf(fmaxf(fmaf(l.x, m.x, xv.x), 0.0f), 1.0f);
    o.y = fminf(fmaxf(fmaf(l.y, m.y, xv.y), 0.0f), 1.0f);
    o.z = fminf(fmaxf(fmaf(l.z, m.z, xv.z), 0.0f), 1.0f);
    o.w = fminf(fmaxf(fmaf(l.w, m.w, xv.w), 0.0f), 1.0f);
    return o;
}

__global__ __launch_bounds__(256) void rrn_clip_kernel(
    const fvec4* __restrict__ x,
    const fvec4* __restrict__ lap,
    const fvec4* __restrict__ mask,
    fvec4* __restrict__ out,
    int n4)
{
    const int tid    = blockIdx.x * blockDim.x + threadIdx.x;
    const int stride = gridDim.x * blockDim.x;

    int i = tid;

    // Main unrolled loop: 12 independent loads issued before any use.
    for (; i + 3 * stride < n4; i += 4 * stride) {
        const int i0 = i;
        const int i1 = i + stride;
        const int i2 = i + 2 * stride;
        const int i3 = i + 3 * stride;

        fvec4 x0 = x[i0],    x1 = x[i1],    x2 = x[i2],    x3 = x[i3];
        fvec4 l0 = lap[i0],  l1 = lap[i1],  l2 = lap[i2],  l3 = lap[i3];
        fvec4 m0 = mask[i0], m1 = mask[i1], m2 = mask[i2], m3 = mask[i3];

        fvec4 o0 = clip_fma(l0, m0, x0);
        fvec4 o1 = clip_fma(l1, m1, x1);
        fvec4 o2 = clip_fma(l2, m2, x2);
        fvec4 o3 = clip_fma(l3, m3, x3);

        __builtin_nontemporal_store(o0, &out[i0]);
        __builtin_nontemporal_store(o1, &out[i1]);
        __builtin_nontemporal_store(o2, &out[i2]);
        __builtin_nontemporal_store(o3, &out[i3]);
    }

    // Remainder.
    for (; i < n4; i += stride) {
        fvec4 o = clip_fma(lap[i], mask[i], x[i]);
        __builtin_nontemporal_store(o, &out[i]);
    }
}

extern "C" void kernel_launch(void* const* d_in, const int* in_sizes, int n_in,
                              void* d_out, int out_size, void* d_ws, size_t ws_size,
                              hipStream_t stream)
{
    const fvec4* x    = (const fvec4*)d_in[0];
    // d_in[1] = eps (scalar) — unused; Bernoulli keep-prob already in mask.
    const fvec4* lap  = (const fvec4*)d_in[2];
    const fvec4* mask = (const fvec4*)d_in[3];
    fvec4* out        = (fvec4*)d_out;

    const int n  = out_size;     // 38,535,168 — divisible by 4
    const int n4 = n >> 2;       // 9,633,792 float4 elements

    // 2048 blocks = 8 blocks/CU on 256 CUs; each thread loops ~18.4 times
    // (4 unrolled outer iterations + remainder).
    const int block = 256;
    const int grid  = 2048;

    rrn_clip_kernel<<<grid, block, 0, stream>>>(x, lap, mask, out, n4);
}